// Round 10
// baseline (228.959 us; speedup 1.0000x reference)
//
#include <hip/hip_runtime.h>

// Dtypes (R1-R6 forensics): floats fp32, edges int32 [E][2], output fp32.
// Workspace intermediates: bf16 (MFMA path).
// Spill law: local arrays with MFMA force scratch; named scalars only.
// R10: XCD-chunked swizzle (m204) + reg-prefetch: 235.6 -> 228.9 us.
// R11-R12 LAW: every __syncthreads drains vmcnt(0). Loads' usable overlap =
//   issue-point -> end-of-iteration barrier. Issue loads at ITERATION TOP.
// R13: attn is memory-system-bound (168MB L2-miss random gathers, LLC-served ~3.7TB/s;
//   flat across 5 structural variants -- treat 57us as its ceiling).
// R14: diag split -> gemm1 counters. R15 (REJ): no-LDS = 84us. R17 (REJ): single-stage
//   132KB = 1 block/CU, staging serialized: +17us. Staging needs >=2 blocks/CU.
// R16 (R7): 512-thr 2-barrier: gemm1 40.8us, MfmaUtil 14.5%, conflicts 2.88M cy (11%).
//   fills x2 @ 40.7us (512MB re-poison) = ~81us fixed harness overhead.
// R18 (R9): dbuf 1-barrier/K-step, loads at top: 225.7us ACCEPTED (best).
// R19 (this): (a) LDS pad -> XOR swizzle (R2-proven, c^=(row&7)<<3, 8-short gran):
//   kills the 11% read-conflict residue, LDS 72->64KB. Addressing-only change.
//   (b) attn re-split 2x10000 (diag, ~4us) to read post-dbuf gemm1 counters.
//   Guard: gemm WRITE ~60MB; conflicts must drop >5x else theory wrong.

typedef __bf16 bf16x8 __attribute__((ext_vector_type(8)));
typedef float  f32x4  __attribute__((ext_vector_type(4)));

__device__ __forceinline__ float bf2f(unsigned short u) {
    union { unsigned int i; float f; } v; v.i = ((unsigned int)u) << 16; return v.f;
}
__device__ __forceinline__ unsigned short f2bf(float f) {
    union { float f; unsigned int i; } v; v.f = f;
    unsigned int x = v.i;
    unsigned int r = (x + 0x7FFFu + ((x >> 16) & 1u)) >> 16;   // RNE
    return (unsigned short)r;
}

#define NNODE 20000
#define ROWS  40000      // B*N
#define DMODEL 256

// ---------- K0: fused prep (blocks 0..1023) + LayerNorm1 (blocks 1024..6023) ----------
__global__ __launch_bounds__(256) void prep_ln1_kernel(
    const float* __restrict__ wq, const float* __restrict__ wk,
    const float* __restrict__ wv, const float* __restrict__ wo,
    const float* __restrict__ bq, const float* __restrict__ bk,
    const float* __restrict__ bv, const float* __restrict__ bo,
    const float* __restrict__ x,
    const float* __restrict__ g1, const float* __restrict__ b1,
    unsigned short* __restrict__ Wqkvt,   // [768][256] bf16
    unsigned short* __restrict__ Wot,     // [256][256] bf16
    float* __restrict__ biasq,            // [768]
    float* __restrict__ biaso,            // [256]
    unsigned short* __restrict__ xn)      // [ROWS][256] bf16
{
    if (blockIdx.x < 1024) {
        int idx = blockIdx.x * 256 + threadIdx.x;
        if (idx < 768 * 256) {
            int n = idx >> 8, k = idx & 255;
            int sel = n >> 8, nl = n & 255;
            const float* w = (sel == 0) ? wq : (sel == 1) ? wk : wv;
            Wqkvt[idx] = f2bf(w[k * 256 + nl]);
        } else {
            int idx2 = idx - 768 * 256;        // [0, 65536)
            int n = idx2 >> 8, k = idx2 & 255;
            Wot[idx2] = f2bf(wo[k * 256 + n]);
        }
        if (idx < 768) {
            const float* bb = (idx < 256) ? bq : (idx < 512) ? bk : bv;
            biasq[idx] = bb[idx & 255];
        }
        if (idx >= 768 && idx < 1024) biaso[idx - 768] = bo[idx - 768];
        return;
    }
    // ---- LN1: half-wave (32 lanes) per row, 8 elems/lane ----
    int wave = threadIdx.x >> 6, lane = threadIdx.x & 63;
    int sub = lane >> 5, hl = lane & 31;
    int m = (blockIdx.x - 1024) * 8 + wave * 2 + sub;
    const float* xp = x + (size_t)m * DMODEL + hl * 8;
    float4 x0 = *(const float4*)xp;
    float4 x1 = *(const float4*)(xp + 4);
    float f[8] = {x0.x, x0.y, x0.z, x0.w, x1.x, x1.y, x1.z, x1.w};
    float s = 0.f, ss = 0.f;
    #pragma unroll
    for (int t = 0; t < 8; ++t) { s += f[t]; ss += f[t]*f[t]; }
    #pragma unroll
    for (int mk = 1; mk < 32; mk <<= 1) { s += __shfl_xor(s, mk); ss += __shfl_xor(ss, mk); }
    float mu  = s * (1.f/256.f);
    float var = ss * (1.f/256.f) - mu*mu;
    float rs  = rsqrtf(var + 1e-3f);
    float4 g0 = *(const float4*)(g1 + hl * 8);
    float4 g1v = *(const float4*)(g1 + hl * 8 + 4);
    float4 b0 = *(const float4*)(b1 + hl * 8);
    float4 b1v = *(const float4*)(b1 + hl * 8 + 4);
    float gg[8] = {g0.x, g0.y, g0.z, g0.w, g1v.x, g1v.y, g1v.z, g1v.w};
    float bb[8] = {b0.x, b0.y, b0.z, b0.w, b1v.x, b1v.y, b1v.z, b1v.w};
    unsigned short o[8];
    #pragma unroll
    for (int t = 0; t < 8; ++t) o[t] = f2bf((f[t] - mu) * rs * gg[t] + bb[t]);
    *(int4*)(xn + (size_t)m * DMODEL + hl * 8) = *(const int4*)o;
}

// ---------- K2/K4: bf16 MFMA GEMM, 128x128 tile, BK=64, dbuf 1-barrier, 512 thr ----------
// C = A[M][256] @ Bt[Ncols][256]^T + bias.  EPI: relu + resid, write fp32; else bf16.
// Wave grid 4m x 2n (32x64 out/wave). Dbuf: As/Bs[2][128][64] XOR-swizzled (64KB,
// 2 blocks/CU). Per iter: {load tile i+2 (TOP), compute buf[i&1], ds_write buf[(i+1)&1],
// barrier}. SWZI: c ^= (row&7)<<3 at 8-short granularity -- reads spread 8 rows over
// all 32 banks (2-way over 16 = free), writes <=2-way. R2-audited bijective.
#define BUFSZ (128 * 64)
#define SWZI(r, c) (((r) << 6) + ((c) ^ (((r) & 7) << 3)))
#define MFMA_BF16(d, a, b) d = __builtin_amdgcn_mfma_f32_16x16x32_bf16(a, b, d, 0, 0, 0)

template<bool EPI>
__global__ __launch_bounds__(512, 2) void gemm_kernel(
    const unsigned short* __restrict__ A,
    const unsigned short* __restrict__ Bt,
    const float* __restrict__ bias,
    void* __restrict__ C,
    const unsigned short* __restrict__ resid,
    int M, int Ncols)
{
    __shared__ __align__(16) unsigned short As[2 * BUFSZ];
    __shared__ __align__(16) unsigned short Bs[2 * BUFSZ];
    int tid  = threadIdx.x;
    int wave = tid >> 6, lane = tid & 63;
    int quad = lane >> 4, l16 = lane & 15;

    // XCD-chunked bijective swizzle (m204)
    int nt_total = Ncols >> 7;
    int nwg = gridDim.x;
    int xcd = blockIdx.x & 7, loc = blockIdx.x >> 3;
    int qq = nwg >> 3, rr = nwg & 7;
    int wid = (xcd < rr) ? (xcd * (qq + 1) + loc)
                         : (rr * (qq + 1) + (xcd - rr) * qq + loc);
    int mt = wid / nt_total;
    int nt = wid - mt * nt_total;
    int m0 = mt * 128, n0 = nt * 128;
    int wm = (wave >> 1) * 32, wn = (wave & 1) * 64;   // 4m x 2n wave grid

    int srow = tid >> 2;            // 0..127
    int scol = (tid & 3) * 16;      // 32B column slot of the 64-short k-slice
    int arow = m0 + srow; if (arow >= M) arow = M - 1;   // tail dup, discarded
    const unsigned short* Ap = A  + (size_t)arow * 256 + scol;
    const unsigned short* Bp = Bt + (size_t)(n0 + srow) * 256 + scol;
    int wi0 = SWZI(srow, scol);
    int wi1 = SWZI(srow, scol + 8);

    f32x4 acc00 = {}, acc01 = {}, acc02 = {}, acc03 = {};
    f32x4 acc10 = {}, acc11 = {}, acc12 = {}, acc13 = {};

    int4 s0a0, s0a1, s0b0, s0b1;    // reg set 0 (tiles 0,2)
    int4 s1a0, s1a1, s1b0, s1b1;    // reg set 1 (tiles 1,3)

#define STAGE_LOAD(S, KT) do {                         \
        S##a0 = *(const int4*)(Ap + (KT) * 64);        \
        S##a1 = *(const int4*)(Ap + (KT) * 64 + 8);    \
        S##b0 = *(const int4*)(Bp + (KT) * 64);        \
        S##b1 = *(const int4*)(Bp + (KT) * 64 + 8);    \
    } while (0)
#define STAGE_WRITE(S, BUF) do {                       \
        *(int4*)&As[(BUF) * BUFSZ + wi0] = S##a0;      \
        *(int4*)&As[(BUF) * BUFSZ + wi1] = S##a1;      \
        *(int4*)&Bs[(BUF) * BUFSZ + wi0] = S##b0;      \
        *(int4*)&Bs[(BUF) * BUFSZ + wi1] = S##b1;      \
    } while (0)
#define COMPUTE(BUF) do {                                                          \
        _Pragma("unroll")                                                          \
        for (int ks = 0; ks < 64; ks += 32) {                                      \
            int ca = ks + quad * 8;                                                \
            int bb = (BUF) * BUFSZ;                                                \
            bf16x8 a0 = *(const bf16x8*)&As[bb + SWZI(wm +  0 + l16, ca)];         \
            bf16x8 a1 = *(const bf16x8*)&As[bb + SWZI(wm + 16 + l16, ca)];         \
            bf16x8 b0 = *(const bf16x8*)&Bs[bb + SWZI(wn +  0 + l16, ca)];         \
            bf16x8 b1 = *(const bf16x8*)&Bs[bb + SWZI(wn + 16 + l16, ca)];         \
            bf16x8 b2 = *(const bf16x8*)&Bs[bb + SWZI(wn + 32 + l16, ca)];         \
            bf16x8 b3 = *(const bf16x8*)&Bs[bb + SWZI(wn + 48 + l16, ca)];         \
            MFMA_BF16(acc00, a0, b0); MFMA_BF16(acc01, a0, b1);                    \
            MFMA_BF16(acc02, a0, b2); MFMA_BF16(acc03, a0, b3);                    \
            MFMA_BF16(acc10, a1, b0); MFMA_BF16(acc11, a1, b1);                    \
            MFMA_BF16(acc12, a1, b2); MFMA_BF16(acc13, a1, b3);                    \
        }                                                                          \
    } while (0)

    // prologue: tiles 0,1 in flight; tile0 -> buf0; one barrier
    STAGE_LOAD(s0, 0);
    STAGE_LOAD(s1, 1);
    STAGE_WRITE(s0, 0);             // compiler waits vmcnt for s0 only
    __syncthreads();                // drains s1 loads too (one-time)

    // iter0: compute tile0(buf0); write tile1->buf1; load tile2 at top
    STAGE_LOAD(s0, 2);
    COMPUTE(0);
    STAGE_WRITE(s1, 1);             // s1 already drained at prologue barrier
    __syncthreads();

    // iter1: compute tile1(buf1); write tile2->buf0; load tile3 at top
    STAGE_LOAD(s1, 3);
    COMPUTE(1);
    STAGE_WRITE(s0, 0);             // s0 drained at iter0 barrier
    __syncthreads();

    // iter2: compute tile2(buf0); write tile3->buf1
    COMPUTE(0);
    STAGE_WRITE(s1, 1);             // s1 drained at iter1 barrier
    __syncthreads();

    // iter3: compute tile3(buf1); no barrier
    COMPUTE(1);

#undef STAGE_LOAD
#undef STAGE_WRITE
#undef COMPUTE

#define EPI_STORE(accv, R, CC) do {                                          \
        int col = n0 + wn + (CC) * 16 + l16;                                 \
        float bb = bias[col];                                                \
        int rowb = m0 + wm + (R) * 16 + quad * 4;                            \
        _Pragma("unroll")                                                    \
        for (int rr = 0; rr < 4; ++rr) {                                     \
            int row = rowb + rr;                                             \
            if (row < M) {                                                   \
                float v = (accv)[rr] + bb;                                   \
                if (EPI) {                                                   \
                    v = fmaxf(v, 0.f);                                       \
                    v += bf2f(resid[(size_t)row * 256 + col]);               \
                    ((float*)C)[(size_t)row * Ncols + col] = v;              \
                } else {                                                     \
                    ((unsigned short*)C)[(size_t)row * Ncols + col] = f2bf(v);\
                }                                                            \
            }                                                                \
        }                                                                    \
    } while (0)

    EPI_STORE(acc00, 0, 0); EPI_STORE(acc01, 0, 1); EPI_STORE(acc02, 0, 2); EPI_STORE(acc03, 0, 3);
    EPI_STORE(acc10, 1, 0); EPI_STORE(acc11, 1, 1); EPI_STORE(acc12, 1, 2); EPI_STORE(acc13, 1, 3);
#undef EPI_STORE
}

// ---------- K3: edge attention + residual + LN2 — wave = node, half-wave = batch ----------
// All 16 K/V gather loads issued into named registers before compute (R9; no spill).
// R19: node0 split again (2x10000, diagnostic) to surface post-dbuf gemm1 counters.
__global__ __launch_bounds__(1024) void attn_kernel(
    const unsigned short* __restrict__ qkv,   // [ROWS][768] bf16: q|k|v
    const int* __restrict__ edges,            // int32 [E][2]
    const unsigned short* __restrict__ xn,    // [ROWS][256] bf16
    const float* __restrict__ g2, const float* __restrict__ b2,
    unsigned short* __restrict__ concat,      // [ROWS][256] bf16
    unsigned short* __restrict__ h2,          // [ROWS][256] bf16
    int node0)
{
    int wave = threadIdx.x >> 6, lane = threadIdx.x & 63;
    int i = node0 + blockIdx.x * 16 + wave;   // node id
    int b = lane >> 5, hl = lane & 31;        // batch half, 8 dims/lane
    size_t m = (size_t)b * NNODE + i;

    int jv = 0;
    if (lane < 8) jv = edges[2 * (i * 8 + lane) + 1];   // chain head: issue first

    int4 qi = *(const int4*)(qkv + m * 768 + hl * 8);
    int4 xi = *(const int4*)(xn + m * DMODEL + hl * 8);   // issued early, used late
    const unsigned short* qs = (const unsigned short*)&qi;
    float qf[8];
    #pragma unroll
    for (int t = 0; t < 8; ++t) qf[t] = bf2f(qs[t]);

#define KVLOAD(E)                                                                  \
    int j##E = __shfl(jv, E);                                                      \
    const unsigned short* kp##E = qkv + ((size_t)b * NNODE + j##E) * 768 + 256 + hl * 8; \
    int4 KI##E = *(const int4*)(kp##E);                                            \
    int4 VI##E = *(const int4*)(kp##E + 256);
    KVLOAD(0) KVLOAD(1) KVLOAD(2) KVLOAD(3)
    KVLOAD(4) KVLOAD(5) KVLOAD(6) KVLOAD(7)
#undef KVLOAD

    float acc[8] = {};
    float den = 0.f;
    const float scale = 0.17677669529663687f;           // 1/sqrt(32)
#define EDGE(E) do {                                                         \
        const unsigned short* ks = (const unsigned short*)&KI##E;            \
        const unsigned short* vs = (const unsigned short*)&VI##E;            \
        float dot = 0.f;                                                     \
        _Pragma("unroll")                                                    \
        for (int t = 0; t < 8; ++t) dot += qf[t] * bf2f(ks[t]);              \
        dot += __shfl_xor(dot, 1);                                           \
        dot += __shfl_xor(dot, 2);            /* head = 4 lanes (dh=32) */   \
        float w = __expf(dot * scale);                                       \
        _Pragma("unroll")                                                    \
        for (int t = 0; t < 8; ++t) acc[t] += w * bf2f(vs[t]);               \
        den += w;                                                            \
    } while (0)
    EDGE(0); EDGE(1); EDGE(2); EDGE(3);
    EDGE(4); EDGE(5); EDGE(6); EDGE(7);
#undef EDGE
    float inv = 1.f / den;

    const unsigned short* xs = (const unsigned short*)&xi;
    float c[8], s = 0.f, ss = 0.f;
    #pragma unroll
    for (int t = 0; t < 8; ++t) { c[t] = bf2f(xs[t]) + acc[t] * inv; s += c[t]; ss += c[t]*c[t]; }
    #pragma unroll
    for (int mk = 1; mk < 32; mk <<= 1) { s += __shfl_xor(s, mk); ss += __shfl_xor(ss, mk); }
    float mu  = s * (1.f/256.f);
    float var = ss * (1.f/256.f) - mu*mu;
    float rs  = rsqrtf(var + 1e-3f);

    float4 ga = *(const float4*)(g2 + hl * 8);
    float4 gb = *(const float4*)(g2 + hl * 8 + 4);
    float4 ba = *(const float4*)(b2 + hl * 8);
    float4 bb = *(const float4*)(b2 + hl * 8 + 4);
    float gg[8] = {ga.x, ga.y, ga.z, ga.w, gb.x, gb.y, gb.z, gb.w};
    float bv[8] = {ba.x, ba.y, ba.z, ba.w, bb.x, bb.y, bb.z, bb.w};
    unsigned short oc[8], oh[8];
    #pragma unroll
    for (int t = 0; t < 8; ++t) {
        oc[t] = f2bf(c[t]);
        oh[t] = f2bf((c[t] - mu) * rs * gg[t] + bv[t]);
    }
    *(int4*)(concat + m * DMODEL + hl * 8) = *(const int4*)oc;
    *(int4*)(h2     + m * DMODEL + hl * 8) = *(const int4*)oh;
}

// ---------- launch ----------
extern "C" void kernel_launch(void* const* d_in, const int* in_sizes, int n_in,
                              void* d_out, int out_size, void* d_ws, size_t ws_size,
                              hipStream_t stream)
{
    const float* x   = (const float*)d_in[0];
    const int* edges = (const int*)d_in[1];
    const float* wq = (const float*)d_in[2];
    const float* bq = (const float*)d_in[3];
    const float* wk = (const float*)d_in[4];
    const float* bk = (const float*)d_in[5];
    const float* wv = (const float*)d_in[6];
    const float* bv = (const float*)d_in[7];
    const float* wo = (const float*)d_in[8];
    const float* bo = (const float*)d_in[9];
    const float* g1 = (const float*)d_in[10];
    const float* b1 = (const float*)d_in[11];
    const float* g2 = (const float*)d_in[12];
    const float* b2 = (const float*)d_in[13];

    char* ws = (char*)d_ws;
    unsigned short* Wqkvt = (unsigned short*)(ws);                    // 393216 B
    unsigned short* Wot   = (unsigned short*)(ws + 393216);           // 131072 B
    float* biasq          = (float*)(ws + 393216 + 131072);           // 3072 B
    float* biaso          = (float*)(ws + 393216 + 131072 + 3072);    // 1024 B
    size_t off = 393216 + 131072 + 4096;
    unsigned short* xn     = (unsigned short*)(ws + off); off += (size_t)ROWS * DMODEL * 2;
    unsigned short* qkv    = (unsigned short*)(ws + off); off += (size_t)ROWS * 768 * 2;
    unsigned short* concat = (unsigned short*)(ws + off); off += (size_t)ROWS * DMODEL * 2;
    unsigned short* h2     = (unsigned short*)(ws + off); off += (size_t)ROWS * DMODEL * 2;

    prep_ln1_kernel<<<1024 + ROWS / 8, 256, 0, stream>>>(
        wq, wk, wv, wo, bq, bk, bv, bo, x, g1, b1, Wqkvt, Wot, biasq, biaso, xn);
    gemm_kernel<false><<<dim3(313 * 6), 512, 0, stream>>>(xn, Wqkvt, biasq, qkv, nullptr, ROWS, 768);
    attn_kernel<<<625, 1024, 0, stream>>>(qkv, edges, xn, g2, b2, concat, h2, 0);
    attn_kernel<<<625, 1024, 0, stream>>>(qkv, edges, xn, g2, b2, concat, h2, 10000);
    gemm_kernel<true><<<dim3(313 * 2), 512, 0, stream>>>(h2, Wot, biaso, d_out, concat, ROWS, 256);
}

// Round 11
// 224.221 us; speedup vs baseline: 1.0211x; 1.0211x over previous
//
#include <hip/hip_runtime.h>

// Dtypes (R1-R6 forensics): floats fp32, edges int32 [E][2], output fp32.
// Workspace intermediates: bf16 (MFMA path).
// Spill law: local arrays with MFMA force scratch; named scalars only.
// R10: XCD-chunked swizzle (m204) + reg-prefetch: 235.6 -> 228.9 us.
// R11-R12 LAW: __syncthreads lowers to s_waitcnt vmcnt(0) lgkmcnt(0); s_barrier --
//   it force-drains prefetch loads no matter where they were issued.
// R13: attn memory-system-bound (168MB L2-fill random gathers ~3.7TB/s; flat across
//   6 structural variants -- 57us treated as its ceiling).
// R15 (REJ): no-LDS GEMM 84us. R17 (REJ): single-stage 132KB -> 1 blk/CU, +17us.
// R16/R18/R19 (measured): 2-barrier pad / dbuf pad / dbuf swizzle ALL ~40-41us gemm1,
//   MfmaUtil 13-14.5%, Occ 31-33%. Swizzle: conflicts 2.88M -> 0, dur UNCHANGED --
//   T2 regime-gate confirmed: stage+vmcnt-drain+barrier is the critical path, not LDS.
//   fills x2 @ 40.5us (512MB re-poison) = ~81us fixed harness overhead.
// R20 (this): T4 essence -- replace __syncthreads with {s_waitcnt lgkmcnt(0);
//   s_barrier} (raw, no vmcnt drain) + sched_barrier fences (rule #18). Global staging
//   loads now live ACROSS barriers; their ds_write consumer carries a COUNTED vmcnt(4)
//   (never 0) via register dependency. LDS ordering fully preserved by lgkmcnt(0)
//   (covers ds_read AND ds_write -> WAR/RAW on both buffers safe). attn merged back
//   (diagnostic split paid out, -4us). Guard: WRITE ~60MB, absmax stable.

typedef __bf16 bf16x8 __attribute__((ext_vector_type(8)));
typedef float  f32x4  __attribute__((ext_vector_type(4)));

__device__ __forceinline__ float bf2f(unsigned short u) {
    union { unsigned int i; float f; } v; v.i = ((unsigned int)u) << 16; return v.f;
}
__device__ __forceinline__ unsigned short f2bf(float f) {
    union { float f; unsigned int i; } v; v.f = f;
    unsigned int x = v.i;
    unsigned int r = (x + 0x7FFFu + ((x >> 16) & 1u)) >> 16;   // RNE
    return (unsigned short)r;
}

#define NNODE 20000
#define ROWS  40000      // B*N
#define DMODEL 256

// ---------- K0: fused prep (blocks 0..1023) + LayerNorm1 (blocks 1024..6023) ----------
__global__ __launch_bounds__(256) void prep_ln1_kernel(
    const float* __restrict__ wq, const float* __restrict__ wk,
    const float* __restrict__ wv, const float* __restrict__ wo,
    const float* __restrict__ bq, const float* __restrict__ bk,
    const float* __restrict__ bv, const float* __restrict__ bo,
    const float* __restrict__ x,
    const float* __restrict__ g1, const float* __restrict__ b1,
    unsigned short* __restrict__ Wqkvt,   // [768][256] bf16
    unsigned short* __restrict__ Wot,     // [256][256] bf16
    float* __restrict__ biasq,            // [768]
    float* __restrict__ biaso,            // [256]
    unsigned short* __restrict__ xn)      // [ROWS][256] bf16
{
    if (blockIdx.x < 1024) {
        int idx = blockIdx.x * 256 + threadIdx.x;
        if (idx < 768 * 256) {
            int n = idx >> 8, k = idx & 255;
            int sel = n >> 8, nl = n & 255;
            const float* w = (sel == 0) ? wq : (sel == 1) ? wk : wv;
            Wqkvt[idx] = f2bf(w[k * 256 + nl]);
        } else {
            int idx2 = idx - 768 * 256;        // [0, 65536)
            int n = idx2 >> 8, k = idx2 & 255;
            Wot[idx2] = f2bf(wo[k * 256 + n]);
        }
        if (idx < 768) {
            const float* bb = (idx < 256) ? bq : (idx < 512) ? bk : bv;
            biasq[idx] = bb[idx & 255];
        }
        if (idx >= 768 && idx < 1024) biaso[idx - 768] = bo[idx - 768];
        return;
    }
    // ---- LN1: half-wave (32 lanes) per row, 8 elems/lane ----
    int wave = threadIdx.x >> 6, lane = threadIdx.x & 63;
    int sub = lane >> 5, hl = lane & 31;
    int m = (blockIdx.x - 1024) * 8 + wave * 2 + sub;
    const float* xp = x + (size_t)m * DMODEL + hl * 8;
    float4 x0 = *(const float4*)xp;
    float4 x1 = *(const float4*)(xp + 4);
    float f[8] = {x0.x, x0.y, x0.z, x0.w, x1.x, x1.y, x1.z, x1.w};
    float s = 0.f, ss = 0.f;
    #pragma unroll
    for (int t = 0; t < 8; ++t) { s += f[t]; ss += f[t]*f[t]; }
    #pragma unroll
    for (int mk = 1; mk < 32; mk <<= 1) { s += __shfl_xor(s, mk); ss += __shfl_xor(ss, mk); }
    float mu  = s * (1.f/256.f);
    float var = ss * (1.f/256.f) - mu*mu;
    float rs  = rsqrtf(var + 1e-3f);
    float4 g0 = *(const float4*)(g1 + hl * 8);
    float4 g1v = *(const float4*)(g1 + hl * 8 + 4);
    float4 b0 = *(const float4*)(b1 + hl * 8);
    float4 b1v = *(const float4*)(b1 + hl * 8 + 4);
    float gg[8] = {g0.x, g0.y, g0.z, g0.w, g1v.x, g1v.y, g1v.z, g1v.w};
    float bb[8] = {b0.x, b0.y, b0.z, b0.w, b1v.x, b1v.y, b1v.z, b1v.w};
    unsigned short o[8];
    #pragma unroll
    for (int t = 0; t < 8; ++t) o[t] = f2bf((f[t] - mu) * rs * gg[t] + bb[t]);
    *(int4*)(xn + (size_t)m * DMODEL + hl * 8) = *(const int4*)o;
}

// ---------- K2/K4: bf16 MFMA GEMM, 128x128 tile, BK=64, dbuf + light barriers ----------
// C = A[M][256] @ Bt[Ncols][256]^T + bias.  EPI: relu + resid, write fp32; else bf16.
// Wave grid 4m x 2n (32x64 out/wave). Dbuf As/Bs[2][128][64] XOR-swizzled (64KB,
// 2 blocks/CU). Per iter: {load tile i+2 (TOP), compute buf[i&1], ds_write buf[(i+1)&1],
// LIGHT_BARRIER}. LIGHT_BARRIER = lgkmcnt(0)+s_barrier -- NO vmcnt drain: staging
// loads stay in flight across barriers; their ds_write use carries counted vmcnt(4).
#define BUFSZ (128 * 64)
#define SWZI(r, c) (((r) << 6) + ((c) ^ (((r) & 7) << 3)))
#define MFMA_BF16(d, a, b) d = __builtin_amdgcn_mfma_f32_16x16x32_bf16(a, b, d, 0, 0, 0)
#define LIGHT_BARRIER() do {                                  \
        __builtin_amdgcn_sched_barrier(0);                    \
        asm volatile("s_waitcnt lgkmcnt(0)" ::: "memory");    \
        __builtin_amdgcn_sched_barrier(0);                    \
        __builtin_amdgcn_s_barrier();                         \
        __builtin_amdgcn_sched_barrier(0);                    \
    } while (0)

template<bool EPI>
__global__ __launch_bounds__(512, 2) void gemm_kernel(
    const unsigned short* __restrict__ A,
    const unsigned short* __restrict__ Bt,
    const float* __restrict__ bias,
    void* __restrict__ C,
    const unsigned short* __restrict__ resid,
    int M, int Ncols)
{
    __shared__ __align__(16) unsigned short As[2 * BUFSZ];
    __shared__ __align__(16) unsigned short Bs[2 * BUFSZ];
    int tid  = threadIdx.x;
    int wave = tid >> 6, lane = tid & 63;
    int quad = lane >> 4, l16 = lane & 15;

    // XCD-chunked bijective swizzle (m204)
    int nt_total = Ncols >> 7;
    int nwg = gridDim.x;
    int xcd = blockIdx.x & 7, loc = blockIdx.x >> 3;
    int qq = nwg >> 3, rr = nwg & 7;
    int wid = (xcd < rr) ? (xcd * (qq + 1) + loc)
                         : (rr * (qq + 1) + (xcd - rr) * qq + loc);
    int mt = wid / nt_total;
    int nt = wid - mt * nt_total;
    int m0 = mt * 128, n0 = nt * 128;
    int wm = (wave >> 1) * 32, wn = (wave & 1) * 64;   // 4m x 2n wave grid

    int srow = tid >> 2;            // 0..127
    int scol = (tid & 3) * 16;      // 32B column slot of the 64-short k-slice
    int arow = m0 + srow; if (arow >= M) arow = M - 1;   // tail dup, discarded
    const unsigned short* Ap = A  + (size_t)arow * 256 + scol;
    const unsigned short* Bp = Bt + (size_t)(n0 + srow) * 256 + scol;
    int wi0 = SWZI(srow, scol);
    int wi1 = SWZI(srow, scol + 8);

    f32x4 acc00 = {}, acc01 = {}, acc02 = {}, acc03 = {};
    f32x4 acc10 = {}, acc11 = {}, acc12 = {}, acc13 = {};

    int4 s0a0, s0a1, s0b0, s0b1;    // reg set 0 (tiles 0,2)
    int4 s1a0, s1a1, s1b0, s1b1;    // reg set 1 (tiles 1,3)

#define STAGE_LOAD(S, KT) do {                         \
        S##a0 = *(const int4*)(Ap + (KT) * 64);        \
        S##a1 = *(const int4*)(Ap + (KT) * 64 + 8);    \
        S##b0 = *(const int4*)(Bp + (KT) * 64);        \
        S##b1 = *(const int4*)(Bp + (KT) * 64 + 8);    \
    } while (0)
#define STAGE_WRITE(S, BUF) do {                       \
        *(int4*)&As[(BUF) * BUFSZ + wi0] = S##a0;      \
        *(int4*)&As[(BUF) * BUFSZ + wi1] = S##a1;      \
        *(int4*)&Bs[(BUF) * BUFSZ + wi0] = S##b0;      \
        *(int4*)&Bs[(BUF) * BUFSZ + wi1] = S##b1;      \
    } while (0)
#define COMPUTE(BUF) do {                                                          \
        _Pragma("unroll")                                                          \
        for (int ks = 0; ks < 64; ks += 32) {                                      \
            int ca = ks + quad * 8;                                                \
            int bb = (BUF) * BUFSZ;                                                \
            bf16x8 a0 = *(const bf16x8*)&As[bb + SWZI(wm +  0 + l16, ca)];         \
            bf16x8 a1 = *(const bf16x8*)&As[bb + SWZI(wm + 16 + l16, ca)];         \
            bf16x8 b0 = *(const bf16x8*)&Bs[bb + SWZI(wn +  0 + l16, ca)];         \
            bf16x8 b1 = *(const bf16x8*)&Bs[bb + SWZI(wn + 16 + l16, ca)];         \
            bf16x8 b2 = *(const bf16x8*)&Bs[bb + SWZI(wn + 32 + l16, ca)];         \
            bf16x8 b3 = *(const bf16x8*)&Bs[bb + SWZI(wn + 48 + l16, ca)];         \
            MFMA_BF16(acc00, a0, b0); MFMA_BF16(acc01, a0, b1);                    \
            MFMA_BF16(acc02, a0, b2); MFMA_BF16(acc03, a0, b3);                    \
            MFMA_BF16(acc10, a1, b0); MFMA_BF16(acc11, a1, b1);                    \
            MFMA_BF16(acc12, a1, b2); MFMA_BF16(acc13, a1, b3);                    \
        }                                                                          \
    } while (0)

    // prologue: tiles 0,1 in flight; tile0 -> buf0 (counted vmcnt via reg dep);
    // light barrier leaves tile1's loads outstanding.
    STAGE_LOAD(s0, 0);
    STAGE_LOAD(s1, 1);
    STAGE_WRITE(s0, 0);
    LIGHT_BARRIER();

    // iter0: load tile2 at top; compute tile0(buf0); write tile1->buf1
    STAGE_LOAD(s0, 2);
    COMPUTE(0);
    STAGE_WRITE(s1, 1);             // waits s1's 4 loads only (vmcnt counted)
    LIGHT_BARRIER();

    // iter1: load tile3 at top; compute tile1(buf1); write tile2->buf0
    STAGE_LOAD(s1, 3);
    COMPUTE(1);
    STAGE_WRITE(s0, 0);             // waits s0's 4 loads only
    LIGHT_BARRIER();

    // iter2: compute tile2(buf0); write tile3->buf1
    COMPUTE(0);
    STAGE_WRITE(s1, 1);
    LIGHT_BARRIER();

    // iter3: compute tile3(buf1); no barrier
    COMPUTE(1);

#undef STAGE_LOAD
#undef STAGE_WRITE
#undef COMPUTE

#define EPI_STORE(accv, R, CC) do {                                          \
        int col = n0 + wn + (CC) * 16 + l16;                                 \
        float bb = bias[col];                                                \
        int rowb = m0 + wm + (R) * 16 + quad * 4;                            \
        _Pragma("unroll")                                                    \
        for (int rr = 0; rr < 4; ++rr) {                                     \
            int row = rowb + rr;                                             \
            if (row < M) {                                                   \
                float v = (accv)[rr] + bb;                                   \
                if (EPI) {                                                   \
                    v = fmaxf(v, 0.f);                                       \
                    v += bf2f(resid[(size_t)row * 256 + col]);               \
                    ((float*)C)[(size_t)row * Ncols + col] = v;              \
                } else {                                                     \
                    ((unsigned short*)C)[(size_t)row * Ncols + col] = f2bf(v);\
                }                                                            \
            }                                                                \
        }                                                                    \
    } while (0)

    EPI_STORE(acc00, 0, 0); EPI_STORE(acc01, 0, 1); EPI_STORE(acc02, 0, 2); EPI_STORE(acc03, 0, 3);
    EPI_STORE(acc10, 1, 0); EPI_STORE(acc11, 1, 1); EPI_STORE(acc12, 1, 2); EPI_STORE(acc13, 1, 3);
#undef EPI_STORE
}

// ---------- K3: edge attention + residual + LN2 — wave = node, half-wave = batch ----------
// All 16 K/V gather loads issued into named registers before compute (R9; no spill).
// Merged single dispatch (1250 blocks x 1024 thr). At its L2-fill random-gather floor.
__global__ __launch_bounds__(1024) void attn_kernel(
    const unsigned short* __restrict__ qkv,   // [ROWS][768] bf16: q|k|v
    const int* __restrict__ edges,            // int32 [E][2]
    const unsigned short* __restrict__ xn,    // [ROWS][256] bf16
    const float* __restrict__ g2, const float* __restrict__ b2,
    unsigned short* __restrict__ concat,      // [ROWS][256] bf16
    unsigned short* __restrict__ h2)          // [ROWS][256] bf16
{
    int wave = threadIdx.x >> 6, lane = threadIdx.x & 63;
    int i = blockIdx.x * 16 + wave;           // node id
    int b = lane >> 5, hl = lane & 31;        // batch half, 8 dims/lane
    size_t m = (size_t)b * NNODE + i;

    int jv = 0;
    if (lane < 8) jv = edges[2 * (i * 8 + lane) + 1];   // chain head: issue first

    int4 qi = *(const int4*)(qkv + m * 768 + hl * 8);
    int4 xi = *(const int4*)(xn + m * DMODEL + hl * 8);   // issued early, used late
    const unsigned short* qs = (const unsigned short*)&qi;
    float qf[8];
    #pragma unroll
    for (int t = 0; t < 8; ++t) qf[t] = bf2f(qs[t]);

#define KVLOAD(E)                                                                  \
    int j##E = __shfl(jv, E);                                                      \
    const unsigned short* kp##E = qkv + ((size_t)b * NNODE + j##E) * 768 + 256 + hl * 8; \
    int4 KI##E = *(const int4*)(kp##E);                                            \
    int4 VI##E = *(const int4*)(kp##E + 256);
    KVLOAD(0) KVLOAD(1) KVLOAD(2) KVLOAD(3)
    KVLOAD(4) KVLOAD(5) KVLOAD(6) KVLOAD(7)
#undef KVLOAD

    float acc[8] = {};
    float den = 0.f;
    const float scale = 0.17677669529663687f;           // 1/sqrt(32)
#define EDGE(E) do {                                                         \
        const unsigned short* ks = (const unsigned short*)&KI##E;            \
        const unsigned short* vs = (const unsigned short*)&VI##E;            \
        float dot = 0.f;                                                     \
        _Pragma("unroll")                                                    \
        for (int t = 0; t < 8; ++t) dot += qf[t] * bf2f(ks[t]);              \
        dot += __shfl_xor(dot, 1);                                           \
        dot += __shfl_xor(dot, 2);            /* head = 4 lanes (dh=32) */   \
        float w = __expf(dot * scale);                                       \
        _Pragma("unroll")                                                    \
        for (int t = 0; t < 8; ++t) acc[t] += w * bf2f(vs[t]);               \
        den += w;                                                            \
    } while (0)
    EDGE(0); EDGE(1); EDGE(2); EDGE(3);
    EDGE(4); EDGE(5); EDGE(6); EDGE(7);
#undef EDGE
    float inv = 1.f / den;

    const unsigned short* xs = (const unsigned short*)&xi;
    float c[8], s = 0.f, ss = 0.f;
    #pragma unroll
    for (int t = 0; t < 8; ++t) { c[t] = bf2f(xs[t]) + acc[t] * inv; s += c[t]; ss += c[t]*c[t]; }
    #pragma unroll
    for (int mk = 1; mk < 32; mk <<= 1) { s += __shfl_xor(s, mk); ss += __shfl_xor(ss, mk); }
    float mu  = s * (1.f/256.f);
    float var = ss * (1.f/256.f) - mu*mu;
    float rs  = rsqrtf(var + 1e-3f);

    float4 ga = *(const float4*)(g2 + hl * 8);
    float4 gb = *(const float4*)(g2 + hl * 8 + 4);
    float4 ba = *(const float4*)(b2 + hl * 8);
    float4 bb = *(const float4*)(b2 + hl * 8 + 4);
    float gg[8] = {ga.x, ga.y, ga.z, ga.w, gb.x, gb.y, gb.z, gb.w};
    float bv[8] = {ba.x, ba.y, ba.z, ba.w, bb.x, bb.y, bb.z, bb.w};
    unsigned short oc[8], oh[8];
    #pragma unroll
    for (int t = 0; t < 8; ++t) {
        oc[t] = f2bf(c[t]);
        oh[t] = f2bf((c[t] - mu) * rs * gg[t] + bv[t]);
    }
    *(int4*)(concat + m * DMODEL + hl * 8) = *(const int4*)oc;
    *(int4*)(h2     + m * DMODEL + hl * 8) = *(const int4*)oh;
}

// ---------- launch ----------
extern "C" void kernel_launch(void* const* d_in, const int* in_sizes, int n_in,
                              void* d_out, int out_size, void* d_ws, size_t ws_size,
                              hipStream_t stream)
{
    const float* x   = (const float*)d_in[0];
    const int* edges = (const int*)d_in[1];
    const float* wq = (const float*)d_in[2];
    const float* bq = (const float*)d_in[3];
    const float* wk = (const float*)d_in[4];
    const float* bk = (const float*)d_in[5];
    const float* wv = (const float*)d_in[6];
    const float* bv = (const float*)d_in[7];
    const float* wo = (const float*)d_in[8];
    const float* bo = (const float*)d_in[9];
    const float* g1 = (const float*)d_in[10];
    const float* b1 = (const float*)d_in[11];
    const float* g2 = (const float*)d_in[12];
    const float* b2 = (const float*)d_in[13];

    char* ws = (char*)d_ws;
    unsigned short* Wqkvt = (unsigned short*)(ws);                    // 393216 B
    unsigned short* Wot   = (unsigned short*)(ws + 393216);           // 131072 B
    float* biasq          = (float*)(ws + 393216 + 131072);           // 3072 B
    float* biaso          = (float*)(ws + 393216 + 131072 + 3072);    // 1024 B
    size_t off = 393216 + 131072 + 4096;
    unsigned short* xn     = (unsigned short*)(ws + off); off += (size_t)ROWS * DMODEL * 2;
    unsigned short* qkv    = (unsigned short*)(ws + off); off += (size_t)ROWS * 768 * 2;
    unsigned short* concat = (unsigned short*)(ws + off); off += (size_t)ROWS * DMODEL * 2;
    unsigned short* h2     = (unsigned short*)(ws + off); off += (size_t)ROWS * DMODEL * 2;

    prep_ln1_kernel<<<1024 + ROWS / 8, 256, 0, stream>>>(
        wq, wk, wv, wo, bq, bk, bv, bo, x, g1, b1, Wqkvt, Wot, biasq, biaso, xn);
    gemm_kernel<false><<<dim3(313 * 6), 512, 0, stream>>>(xn, Wqkvt, biasq, qkv, nullptr, ROWS, 768);
    attn_kernel<<<NNODE / 16, 1024, 0, stream>>>(qkv, edges, xn, g2, b2, concat, h2);
    gemm_kernel<true><<<dim3(313 * 2), 512, 0, stream>>>(h2, Wot, biaso, d_out, concat, ROWS, 256);
}

// Round 12
// 218.327 us; speedup vs baseline: 1.0487x; 1.0270x over previous
//
#include <hip/hip_runtime.h>

// Dtypes (R1-R6 forensics): floats fp32, edges int32 [E][2], output fp32.
// Workspace intermediates: bf16 (MFMA path).
// Spill law: local arrays with MFMA force scratch; named scalars only.
// R10: XCD-chunked swizzle (m204) + reg-prefetch: 235.6 -> 228.9 us.
// R11-R12 LAW: __syncthreads = s_waitcnt vmcnt(0) lgkmcnt(0) + s_barrier.
// R13: attn memory-system-bound (168MB L2-fill random gathers; flat across 6 variants;
//   57us = its ceiling).
// R15 (REJ): no-LDS GEMM 84us. R17 (REJ): single-stage 132KB -> 1 blk/CU +17us.
// R16/R18/R19: pad/dbuf/swizzle all ~40us gemm1; swizzle zeroed conflicts, dur flat
//   (T2 regime-gate). fills x2 @ 40.5us = ~81us fixed harness overhead.
// R20 (R11): LIGHT_BARRIER (lgkmcnt-only) dbuf: 225.7 -> 224.2 ACCEPTED (best).
//   Counters across ALL gemm variants: MfmaUtil ~14%, Occ 31-33%, no spill, FETCH tiny
//   -> latency-bound at 16 waves/CU. The schedule isn't the limiter; wave count is.
// R21 (this): 1024-thr gemm blocks, wave grid 4m x 4n (32x32/wave), same 128x128 tile,
//   same dbuf+swizzle+light-barrier schedule. Per-wave acc 16 + staging 16 VGPR ~50
//   total; __launch_bounds__(1024,8) caps 64 VGPR -> 32 waves/CU (2 blocks) possible,
//   2x latency hiding. Guard: WRITE ~60MB (VGPR>64 spill signature); null => the
//   4-iter L2-latency chain is the floor, move to split-K or declare.

typedef __bf16 bf16x8 __attribute__((ext_vector_type(8)));
typedef float  f32x4  __attribute__((ext_vector_type(4)));

__device__ __forceinline__ float bf2f(unsigned short u) {
    union { unsigned int i; float f; } v; v.i = ((unsigned int)u) << 16; return v.f;
}
__device__ __forceinline__ unsigned short f2bf(float f) {
    union { float f; unsigned int i; } v; v.f = f;
    unsigned int x = v.i;
    unsigned int r = (x + 0x7FFFu + ((x >> 16) & 1u)) >> 16;   // RNE
    return (unsigned short)r;
}

#define NNODE 20000
#define ROWS  40000      // B*N
#define DMODEL 256

// ---------- K0: fused prep (blocks 0..1023) + LayerNorm1 (blocks 1024..6023) ----------
__global__ __launch_bounds__(256) void prep_ln1_kernel(
    const float* __restrict__ wq, const float* __restrict__ wk,
    const float* __restrict__ wv, const float* __restrict__ wo,
    const float* __restrict__ bq, const float* __restrict__ bk,
    const float* __restrict__ bv, const float* __restrict__ bo,
    const float* __restrict__ x,
    const float* __restrict__ g1, const float* __restrict__ b1,
    unsigned short* __restrict__ Wqkvt,   // [768][256] bf16
    unsigned short* __restrict__ Wot,     // [256][256] bf16
    float* __restrict__ biasq,            // [768]
    float* __restrict__ biaso,            // [256]
    unsigned short* __restrict__ xn)      // [ROWS][256] bf16
{
    if (blockIdx.x < 1024) {
        int idx = blockIdx.x * 256 + threadIdx.x;
        if (idx < 768 * 256) {
            int n = idx >> 8, k = idx & 255;
            int sel = n >> 8, nl = n & 255;
            const float* w = (sel == 0) ? wq : (sel == 1) ? wk : wv;
            Wqkvt[idx] = f2bf(w[k * 256 + nl]);
        } else {
            int idx2 = idx - 768 * 256;        // [0, 65536)
            int n = idx2 >> 8, k = idx2 & 255;
            Wot[idx2] = f2bf(wo[k * 256 + n]);
        }
        if (idx < 768) {
            const float* bb = (idx < 256) ? bq : (idx < 512) ? bk : bv;
            biasq[idx] = bb[idx & 255];
        }
        if (idx >= 768 && idx < 1024) biaso[idx - 768] = bo[idx - 768];
        return;
    }
    // ---- LN1: half-wave (32 lanes) per row, 8 elems/lane ----
    int wave = threadIdx.x >> 6, lane = threadIdx.x & 63;
    int sub = lane >> 5, hl = lane & 31;
    int m = (blockIdx.x - 1024) * 8 + wave * 2 + sub;
    const float* xp = x + (size_t)m * DMODEL + hl * 8;
    float4 x0 = *(const float4*)xp;
    float4 x1 = *(const float4*)(xp + 4);
    float f[8] = {x0.x, x0.y, x0.z, x0.w, x1.x, x1.y, x1.z, x1.w};
    float s = 0.f, ss = 0.f;
    #pragma unroll
    for (int t = 0; t < 8; ++t) { s += f[t]; ss += f[t]*f[t]; }
    #pragma unroll
    for (int mk = 1; mk < 32; mk <<= 1) { s += __shfl_xor(s, mk); ss += __shfl_xor(ss, mk); }
    float mu  = s * (1.f/256.f);
    float var = ss * (1.f/256.f) - mu*mu;
    float rs  = rsqrtf(var + 1e-3f);
    float4 g0 = *(const float4*)(g1 + hl * 8);
    float4 g1v = *(const float4*)(g1 + hl * 8 + 4);
    float4 b0 = *(const float4*)(b1 + hl * 8);
    float4 b1v = *(const float4*)(b1 + hl * 8 + 4);
    float gg[8] = {g0.x, g0.y, g0.z, g0.w, g1v.x, g1v.y, g1v.z, g1v.w};
    float bb[8] = {b0.x, b0.y, b0.z, b0.w, b1v.x, b1v.y, b1v.z, b1v.w};
    unsigned short o[8];
    #pragma unroll
    for (int t = 0; t < 8; ++t) o[t] = f2bf((f[t] - mu) * rs * gg[t] + bb[t]);
    *(int4*)(xn + (size_t)m * DMODEL + hl * 8) = *(const int4*)o;
}

// ---------- K2/K4: bf16 MFMA GEMM, 128x128 tile, 1024 thr / 16 waves, dbuf ----------
// C = A[M][256] @ Bt[Ncols][256]^T + bias.  EPI: relu + resid, write fp32; else bf16.
// Wave grid 4m x 4n (32x32 out/wave: acc 16 VGPR, 2a+2b reads per 4 MFMA).
// Dbuf As/Bs[2][128][64] XOR-swizzled (64KB, 2 blocks/CU -> 32 waves/CU).
// Per iter: {load tile i+2 (TOP), compute buf[i&1], ds_write buf[(i+1)&1],
// LIGHT_BARRIER (lgkmcnt only -- staging loads live across barriers, counted vmcnt)}.
#define BUFSZ (128 * 64)
#define SWZI(r, c) (((r) << 6) + ((c) ^ (((r) & 7) << 3)))
#define MFMA_BF16(d, a, b) d = __builtin_amdgcn_mfma_f32_16x16x32_bf16(a, b, d, 0, 0, 0)
#define LIGHT_BARRIER() do {                                  \
        __builtin_amdgcn_sched_barrier(0);                    \
        asm volatile("s_waitcnt lgkmcnt(0)" ::: "memory");    \
        __builtin_amdgcn_sched_barrier(0);                    \
        __builtin_amdgcn_s_barrier();                         \
        __builtin_amdgcn_sched_barrier(0);                    \
    } while (0)

template<bool EPI>
__global__ __launch_bounds__(1024, 8) void gemm_kernel(
    const unsigned short* __restrict__ A,
    const unsigned short* __restrict__ Bt,
    const float* __restrict__ bias,
    void* __restrict__ C,
    const unsigned short* __restrict__ resid,
    int M, int Ncols)
{
    __shared__ __align__(16) unsigned short As[2 * BUFSZ];
    __shared__ __align__(16) unsigned short Bs[2 * BUFSZ];
    int tid  = threadIdx.x;
    int wave = tid >> 6, lane = tid & 63;
    int quad = lane >> 4, l16 = lane & 15;

    // XCD-chunked bijective swizzle (m204)
    int nt_total = Ncols >> 7;
    int nwg = gridDim.x;
    int xcd = blockIdx.x & 7, loc = blockIdx.x >> 3;
    int qq = nwg >> 3, rr = nwg & 7;
    int wid = (xcd < rr) ? (xcd * (qq + 1) + loc)
                         : (rr * (qq + 1) + (xcd - rr) * qq + loc);
    int mt = wid / nt_total;
    int nt = wid - mt * nt_total;
    int m0 = mt * 128, n0 = nt * 128;
    int wm = (wave >> 2) * 32, wn = (wave & 3) * 32;   // 4m x 4n wave grid

    int srow = tid >> 3;            // 0..127
    int scol = (tid & 7) * 8;       // 16B slot of the 64-short k-slice
    int arow = m0 + srow; if (arow >= M) arow = M - 1;   // tail dup, discarded
    const unsigned short* Ap = A  + (size_t)arow * 256 + scol;
    const unsigned short* Bp = Bt + (size_t)(n0 + srow) * 256 + scol;
    int wi0 = SWZI(srow, scol);

    f32x4 acc00 = {}, acc01 = {}, acc10 = {}, acc11 = {};

    int4 s0a, s0b;                  // reg set 0 (tiles 0,2)
    int4 s1a, s1b;                  // reg set 1 (tiles 1,3)

#define STAGE_LOAD(S, KT) do {                         \
        S##a = *(const int4*)(Ap + (KT) * 64);         \
        S##b = *(const int4*)(Bp + (KT) * 64);         \
    } while (0)
#define STAGE_WRITE(S, BUF) do {                       \
        *(int4*)&As[(BUF) * BUFSZ + wi0] = S##a;       \
        *(int4*)&Bs[(BUF) * BUFSZ + wi0] = S##b;       \
    } while (0)
#define COMPUTE(BUF) do {                                                          \
        _Pragma("unroll")                                                          \
        for (int ks = 0; ks < 64; ks += 32) {                                      \
            int ca = ks + quad * 8;                                                \
            int bb = (BUF) * BUFSZ;                                                \
            bf16x8 a0 = *(const bf16x8*)&As[bb + SWZI(wm +  0 + l16, ca)];         \
            bf16x8 a1 = *(const bf16x8*)&As[bb + SWZI(wm + 16 + l16, ca)];         \
            bf16x8 b0 = *(const bf16x8*)&Bs[bb + SWZI(wn +  0 + l16, ca)];         \
            bf16x8 b1 = *(const bf16x8*)&Bs[bb + SWZI(wn + 16 + l16, ca)];         \
            MFMA_BF16(acc00, a0, b0); MFMA_BF16(acc01, a0, b1);                    \
            MFMA_BF16(acc10, a1, b0); MFMA_BF16(acc11, a1, b1);                    \
        }                                                                          \
    } while (0)

    // prologue: tiles 0,1 in flight; tile0 -> buf0; light barrier (tile1 stays in flight)
    STAGE_LOAD(s0, 0);
    STAGE_LOAD(s1, 1);
    STAGE_WRITE(s0, 0);
    LIGHT_BARRIER();

    // iter0: load tile2 at top; compute tile0(buf0); write tile1->buf1
    STAGE_LOAD(s0, 2);
    COMPUTE(0);
    STAGE_WRITE(s1, 1);             // counted vmcnt (waits s1's 2 loads only)
    LIGHT_BARRIER();

    // iter1: load tile3 at top; compute tile1(buf1); write tile2->buf0
    STAGE_LOAD(s1, 3);
    COMPUTE(1);
    STAGE_WRITE(s0, 0);
    LIGHT_BARRIER();

    // iter2: compute tile2(buf0); write tile3->buf1
    COMPUTE(0);
    STAGE_WRITE(s1, 1);
    LIGHT_BARRIER();

    // iter3: compute tile3(buf1); no barrier
    COMPUTE(1);

#undef STAGE_LOAD
#undef STAGE_WRITE
#undef COMPUTE

#define EPI_STORE(accv, R, CC) do {                                          \
        int col = n0 + wn + (CC) * 16 + l16;                                 \
        float bb = bias[col];                                                \
        int rowb = m0 + wm + (R) * 16 + quad * 4;                            \
        _Pragma("unroll")                                                    \
        for (int rr = 0; rr < 4; ++rr) {                                     \
            int row = rowb + rr;                                             \
            if (row < M) {                                                   \
                float v = (accv)[rr] + bb;                                   \
                if (EPI) {                                                   \
                    v = fmaxf(v, 0.f);                                       \
                    v += bf2f(resid[(size_t)row * 256 + col]);               \
                    ((float*)C)[(size_t)row * Ncols + col] = v;              \
                } else {                                                     \
                    ((unsigned short*)C)[(size_t)row * Ncols + col] = f2bf(v);\
                }                                                            \
            }                                                                \
        }                                                                    \
    } while (0)

    EPI_STORE(acc00, 0, 0); EPI_STORE(acc01, 0, 1);
    EPI_STORE(acc10, 1, 0); EPI_STORE(acc11, 1, 1);
#undef EPI_STORE
}

// ---------- K3: edge attention + residual + LN2 — wave = node, half-wave = batch ----------
// All 16 K/V gather loads issued into named registers before compute (R9; no spill).
// Merged single dispatch (1250 blocks x 1024 thr). At its L2-fill random-gather floor.
__global__ __launch_bounds__(1024) void attn_kernel(
    const unsigned short* __restrict__ qkv,   // [ROWS][768] bf16: q|k|v
    const int* __restrict__ edges,            // int32 [E][2]
    const unsigned short* __restrict__ xn,    // [ROWS][256] bf16
    const float* __restrict__ g2, const float* __restrict__ b2,
    unsigned short* __restrict__ concat,      // [ROWS][256] bf16
    unsigned short* __restrict__ h2)          // [ROWS][256] bf16
{
    int wave = threadIdx.x >> 6, lane = threadIdx.x & 63;
    int i = blockIdx.x * 16 + wave;           // node id
    int b = lane >> 5, hl = lane & 31;        // batch half, 8 dims/lane
    size_t m = (size_t)b * NNODE + i;

    int jv = 0;
    if (lane < 8) jv = edges[2 * (i * 8 + lane) + 1];   // chain head: issue first

    int4 qi = *(const int4*)(qkv + m * 768 + hl * 8);
    int4 xi = *(const int4*)(xn + m * DMODEL + hl * 8);   // issued early, used late
    const unsigned short* qs = (const unsigned short*)&qi;
    float qf[8];
    #pragma unroll
    for (int t = 0; t < 8; ++t) qf[t] = bf2f(qs[t]);

#define KVLOAD(E)                                                                  \
    int j##E = __shfl(jv, E);                                                      \
    const unsigned short* kp##E = qkv + ((size_t)b * NNODE + j##E) * 768 + 256 + hl * 8; \
    int4 KI##E = *(const int4*)(kp##E);                                            \
    int4 VI##E = *(const int4*)(kp##E + 256);
    KVLOAD(0) KVLOAD(1) KVLOAD(2) KVLOAD(3)
    KVLOAD(4) KVLOAD(5) KVLOAD(6) KVLOAD(7)
#undef KVLOAD

    float acc[8] = {};
    float den = 0.f;
    const float scale = 0.17677669529663687f;           // 1/sqrt(32)
#define EDGE(E) do {                                                         \
        const unsigned short* ks = (const unsigned short*)&KI##E;            \
        const unsigned short* vs = (const unsigned short*)&VI##E;            \
        float dot = 0.f;                                                     \
        _Pragma("unroll")                                                    \
        for (int t = 0; t < 8; ++t) dot += qf[t] * bf2f(ks[t]);              \
        dot += __shfl_xor(dot, 1);                                           \
        dot += __shfl_xor(dot, 2);            /* head = 4 lanes (dh=32) */   \
        float w = __expf(dot * scale);                                       \
        _Pragma("unroll")                                                    \
        for (int t = 0; t < 8; ++t) acc[t] += w * bf2f(vs[t]);               \
        den += w;                                                            \
    } while (0)
    EDGE(0); EDGE(1); EDGE(2); EDGE(3);
    EDGE(4); EDGE(5); EDGE(6); EDGE(7);
#undef EDGE
    float inv = 1.f / den;

    const unsigned short* xs = (const unsigned short*)&xi;
    float c[8], s = 0.f, ss = 0.f;
    #pragma unroll
    for (int t = 0; t < 8; ++t) { c[t] = bf2f(xs[t]) + acc[t] * inv; s += c[t]; ss += c[t]*c[t]; }
    #pragma unroll
    for (int mk = 1; mk < 32; mk <<= 1) { s += __shfl_xor(s, mk); ss += __shfl_xor(ss, mk); }
    float mu  = s * (1.f/256.f);
    float var = ss * (1.f/256.f) - mu*mu;
    float rs  = rsqrtf(var + 1e-3f);

    float4 ga = *(const float4*)(g2 + hl * 8);
    float4 gb = *(const float4*)(g2 + hl * 8 + 4);
    float4 ba = *(const float4*)(b2 + hl * 8);
    float4 bb = *(const float4*)(b2 + hl * 8 + 4);
    float gg[8] = {ga.x, ga.y, ga.z, ga.w, gb.x, gb.y, gb.z, gb.w};
    float bv[8] = {ba.x, ba.y, ba.z, ba.w, bb.x, bb.y, bb.z, bb.w};
    unsigned short oc[8], oh[8];
    #pragma unroll
    for (int t = 0; t < 8; ++t) {
        oc[t] = f2bf(c[t]);
        oh[t] = f2bf((c[t] - mu) * rs * gg[t] + bv[t]);
    }
    *(int4*)(concat + m * DMODEL + hl * 8) = *(const int4*)oc;
    *(int4*)(h2     + m * DMODEL + hl * 8) = *(const int4*)oh;
}

// ---------- launch ----------
extern "C" void kernel_launch(void* const* d_in, const int* in_sizes, int n_in,
                              void* d_out, int out_size, void* d_ws, size_t ws_size,
                              hipStream_t stream)
{
    const float* x   = (const float*)d_in[0];
    const int* edges = (const int*)d_in[1];
    const float* wq = (const float*)d_in[2];
    const float* bq = (const float*)d_in[3];
    const float* wk = (const float*)d_in[4];
    const float* bk = (const float*)d_in[5];
    const float* wv = (const float*)d_in[6];
    const float* bv = (const float*)d_in[7];
    const float* wo = (const float*)d_in[8];
    const float* bo = (const float*)d_in[9];
    const float* g1 = (const float*)d_in[10];
    const float* b1 = (const float*)d_in[11];
    const float* g2 = (const float*)d_in[12];
    const float* b2 = (const float*)d_in[13];

    char* ws = (char*)d_ws;
    unsigned short* Wqkvt = (unsigned short*)(ws);                    // 393216 B
    unsigned short* Wot   = (unsigned short*)(ws + 393216);           // 131072 B
    float* biasq          = (float*)(ws + 393216 + 131072);           // 3072 B
    float* biaso          = (float*)(ws + 393216 + 131072 + 3072);    // 1024 B
    size_t off = 393216 + 131072 + 4096;
    unsigned short* xn     = (unsigned short*)(ws + off); off += (size_t)ROWS * DMODEL * 2;
    unsigned short* qkv    = (unsigned short*)(ws + off); off += (size_t)ROWS * 768 * 2;
    unsigned short* concat = (unsigned short*)(ws + off); off += (size_t)ROWS * DMODEL * 2;
    unsigned short* h2     = (unsigned short*)(ws + off); off += (size_t)ROWS * DMODEL * 2;

    prep_ln1_kernel<<<1024 + ROWS / 8, 256, 0, stream>>>(
        wq, wk, wv, wo, bq, bk, bv, bo, x, g1, b1, Wqkvt, Wot, biasq, biaso, xn);
    gemm_kernel<false><<<dim3(313 * 6), 1024, 0, stream>>>(xn, Wqkvt, biasq, qkv, nullptr, ROWS, 768);
    attn_kernel<<<NNODE / 16, 1024, 0, stream>>>(qkv, edges, xn, g2, b2, concat, h2);
    gemm_kernel<true><<<dim3(313 * 2), 1024, 0, stream>>>(h2, Wot, biaso, d_out, concat, ROWS, 256);
}

// Round 13
// 213.155 us; speedup vs baseline: 1.0741x; 1.0243x over previous
//
#include <hip/hip_runtime.h>

// Dtypes (R1-R6 forensics): floats fp32, edges int32 [E][2], output fp32.
// Workspace intermediates: bf16 (MFMA path).
// Spill law: local arrays with MFMA force scratch; named scalars only (const-idx ok).
// R10: XCD-chunked swizzle (m204) + reg-prefetch: 235.6 -> 228.9 us.
// R11-R12 LAW: __syncthreads = s_waitcnt vmcnt(0) lgkmcnt(0) + s_barrier.
// R13: attn memory-system-bound: 213MB/dispatch @ ~3.7TB/s random-gather ceiling,
//   flat across 7 variants. Only traffic reduction can move it (window/fp8 = risky).
// R15 (REJ): no-LDS GEMM 84us. R17 (REJ): single-stage 132KB -> 1 blk/CU +17us.
// R16/R18/R19: pad/dbuf/swizzle all ~40us gemm1; swizzle zeroed conflicts, dur flat.
//   fills x2 @ 40.5us = ~81us fixed harness overhead.
// R20 (R11): LIGHT_BARRIER dbuf: 224.2 ACCEPTED.
// R21 (R12): 1024-thr 16-wave gemm (32x32/wave): 218.3 ACCEPTED (best). Occupancy was
//   the gemm limiter; 2 blocks/CU x 16 waves = 32 waves/CU now reachable.
// R22 (this): (a) prep weight-transpose was uncoalesced (1KB-stride reads, ~16MB
//   over-fetch) -> 64x64 LDS tile transpose, 64 blocks. (b) gemm: STAGE_WRITE hoisted
//   BEFORE COMPUTE (ds_writes drain under MFMA, not at the lgkmcnt barrier). WAR safe:
//   target buffer's readers finished before previous barrier. (c) T5 setprio(1) around
//   MFMA cluster (role-diverse dbuf phases = m224 precondition; m190 null at worst).
//   Guards: absmax 0.03125 (transpose value-exact), gemm WRITE ~60MB.

typedef __bf16 bf16x8 __attribute__((ext_vector_type(8)));
typedef float  f32x4  __attribute__((ext_vector_type(4)));

__device__ __forceinline__ float bf2f(unsigned short u) {
    union { unsigned int i; float f; } v; v.i = ((unsigned int)u) << 16; return v.f;
}
__device__ __forceinline__ unsigned short f2bf(float f) {
    union { float f; unsigned int i; } v; v.f = f;
    unsigned int x = v.i;
    unsigned int r = (x + 0x7FFFu + ((x >> 16) & 1u)) >> 16;   // RNE
    return (unsigned short)r;
}

#define NNODE 20000
#define ROWS  40000      // B*N
#define DMODEL 256

// ---------- K0: prep (blocks 0..64: transpose+bias) + LayerNorm1 (blocks 65..5064) ----------
// Blocks 0..47: Wqkvt 64x64 tile transpose (sel = t/16). Blocks 48..63: Wot tiles.
// Block 64: biases. Blocks 65+: LN1 (half-wave per row).
__global__ __launch_bounds__(256) void prep_ln1_kernel(
    const float* __restrict__ wq, const float* __restrict__ wk,
    const float* __restrict__ wv, const float* __restrict__ wo,
    const float* __restrict__ bq, const float* __restrict__ bk,
    const float* __restrict__ bv, const float* __restrict__ bo,
    const float* __restrict__ x,
    const float* __restrict__ g1, const float* __restrict__ b1,
    unsigned short* __restrict__ Wqkvt,   // [768][256] bf16
    unsigned short* __restrict__ Wot,     // [256][256] bf16
    float* __restrict__ biasq,            // [768]
    float* __restrict__ biaso,            // [256]
    unsigned short* __restrict__ xn)      // [ROWS][256] bf16
{
    if (blockIdx.x < 64) {
        __shared__ unsigned short lds[64 * 72];   // 64x64 tile, +8 pad
        int t = blockIdx.x;
        const float* w;
        unsigned short* outp;
        int k0, n0, orow_base;
        if (t < 48) {
            int sel = t >> 4, tt = t & 15;
            w = (sel == 0) ? wq : (sel == 1) ? wk : wv;
            k0 = (tt & 3) * 64; n0 = (tt >> 2) * 64;
            outp = Wqkvt; orow_base = sel * 256 + n0;
        } else {
            int tt = t - 48;
            w = wo;
            k0 = (tt & 3) * 64; n0 = (tt >> 2) * 64;
            outp = Wot; orow_base = n0;
        }
        int tid = threadIdx.x;
        int r = tid >> 2, cseg = (tid & 3) * 16;
        const float* wp = w + (size_t)(k0 + r) * 256 + n0 + cseg;   // coalesced
        float4 v0 = *(const float4*)(wp);
        float4 v1 = *(const float4*)(wp + 4);
        float4 v2 = *(const float4*)(wp + 8);
        float4 v3 = *(const float4*)(wp + 12);
        float vv[16] = {v0.x,v0.y,v0.z,v0.w, v1.x,v1.y,v1.z,v1.w,
                        v2.x,v2.y,v2.z,v2.w, v3.x,v3.y,v3.z,v3.w};
        #pragma unroll
        for (int j = 0; j < 16; ++j) lds[r * 72 + cseg + j] = f2bf(vv[j]);
        __syncthreads();
        int orow = tid >> 2, oseg = (tid & 3) * 16;
        __align__(16) unsigned short o[16];
        #pragma unroll
        for (int j = 0; j < 16; ++j) o[j] = lds[(oseg + j) * 72 + orow];
        unsigned short* op = outp + (size_t)(orow_base + orow) * 256 + k0 + oseg;
        *(int4*)(op)     = ((const int4*)o)[0];     // coalesced 32B/thread
        *(int4*)(op + 8) = ((const int4*)o)[1];
        return;
    }
    if (blockIdx.x == 64) {
        int tid = threadIdx.x;
        #pragma unroll
        for (int rr = 0; rr < 4; ++rr) {
            int idx = rr * 256 + tid;
            if (idx < 768) {
                const float* bb = (idx < 256) ? bq : (idx < 512) ? bk : bv;
                biasq[idx] = bb[idx & 255];
            } else {
                biaso[idx - 768] = bo[idx - 768];
            }
        }
        return;
    }
    // ---- LN1: half-wave (32 lanes) per row, 8 elems/lane ----
    int wave = threadIdx.x >> 6, lane = threadIdx.x & 63;
    int sub = lane >> 5, hl = lane & 31;
    int m = (blockIdx.x - 65) * 8 + wave * 2 + sub;
    const float* xp = x + (size_t)m * DMODEL + hl * 8;
    float4 x0 = *(const float4*)xp;
    float4 x1 = *(const float4*)(xp + 4);
    float f[8] = {x0.x, x0.y, x0.z, x0.w, x1.x, x1.y, x1.z, x1.w};
    float s = 0.f, ss = 0.f;
    #pragma unroll
    for (int t = 0; t < 8; ++t) { s += f[t]; ss += f[t]*f[t]; }
    #pragma unroll
    for (int mk = 1; mk < 32; mk <<= 1) { s += __shfl_xor(s, mk); ss += __shfl_xor(ss, mk); }
    float mu  = s * (1.f/256.f);
    float var = ss * (1.f/256.f) - mu*mu;
    float rs  = rsqrtf(var + 1e-3f);
    float4 g0 = *(const float4*)(g1 + hl * 8);
    float4 g1v = *(const float4*)(g1 + hl * 8 + 4);
    float4 b0 = *(const float4*)(b1 + hl * 8);
    float4 b1v = *(const float4*)(b1 + hl * 8 + 4);
    float gg[8] = {g0.x, g0.y, g0.z, g0.w, g1v.x, g1v.y, g1v.z, g1v.w};
    float bb[8] = {b0.x, b0.y, b0.z, b0.w, b1v.x, b1v.y, b1v.z, b1v.w};
    unsigned short o[8];
    #pragma unroll
    for (int t = 0; t < 8; ++t) o[t] = f2bf((f[t] - mu) * rs * gg[t] + bb[t]);
    *(int4*)(xn + (size_t)m * DMODEL + hl * 8) = *(const int4*)o;
}

// ---------- K2/K4: bf16 MFMA GEMM, 128x128 tile, 1024 thr / 16 waves, dbuf ----------
// C = A[M][256] @ Bt[Ncols][256]^T + bias.  EPI: relu + resid, write fp32; else bf16.
// Wave grid 4m x 4n (32x32 out/wave). Dbuf As/Bs[2][128][64] XOR-swizzled (64KB,
// 2 blocks/CU -> 32 waves/CU). Per iter: {load tile i+2 (TOP), ds_write tile i+1
// (drains under MFMA), setprio(1) COMPUTE buf[i&1] setprio(0), LIGHT_BARRIER}.
#define BUFSZ (128 * 64)
#define SWZI(r, c) (((r) << 6) + ((c) ^ (((r) & 7) << 3)))
#define MFMA_BF16(d, a, b) d = __builtin_amdgcn_mfma_f32_16x16x32_bf16(a, b, d, 0, 0, 0)
#define LIGHT_BARRIER() do {                                  \
        __builtin_amdgcn_sched_barrier(0);                    \
        asm volatile("s_waitcnt lgkmcnt(0)" ::: "memory");    \
        __builtin_amdgcn_sched_barrier(0);                    \
        __builtin_amdgcn_s_barrier();                         \
        __builtin_amdgcn_sched_barrier(0);                    \
    } while (0)

template<bool EPI>
__global__ __launch_bounds__(1024, 8) void gemm_kernel(
    const unsigned short* __restrict__ A,
    const unsigned short* __restrict__ Bt,
    const float* __restrict__ bias,
    void* __restrict__ C,
    const unsigned short* __restrict__ resid,
    int M, int Ncols)
{
    __shared__ __align__(16) unsigned short As[2 * BUFSZ];
    __shared__ __align__(16) unsigned short Bs[2 * BUFSZ];
    int tid  = threadIdx.x;
    int wave = tid >> 6, lane = tid & 63;
    int quad = lane >> 4, l16 = lane & 15;

    // XCD-chunked bijective swizzle (m204)
    int nt_total = Ncols >> 7;
    int nwg = gridDim.x;
    int xcd = blockIdx.x & 7, loc = blockIdx.x >> 3;
    int qq = nwg >> 3, rr = nwg & 7;
    int wid = (xcd < rr) ? (xcd * (qq + 1) + loc)
                         : (rr * (qq + 1) + (xcd - rr) * qq + loc);
    int mt = wid / nt_total;
    int nt = wid - mt * nt_total;
    int m0 = mt * 128, n0 = nt * 128;
    int wm = (wave >> 2) * 32, wn = (wave & 3) * 32;   // 4m x 4n wave grid

    int srow = tid >> 3;            // 0..127
    int scol = (tid & 7) * 8;       // 16B slot of the 64-short k-slice
    int arow = m0 + srow; if (arow >= M) arow = M - 1;   // tail dup, discarded
    const unsigned short* Ap = A  + (size_t)arow * 256 + scol;
    const unsigned short* Bp = Bt + (size_t)(n0 + srow) * 256 + scol;
    int wi0 = SWZI(srow, scol);

    f32x4 acc00 = {}, acc01 = {}, acc10 = {}, acc11 = {};

    int4 s0a, s0b;                  // reg set 0 (tiles 0,2)
    int4 s1a, s1b;                  // reg set 1 (tiles 1,3)

#define STAGE_LOAD(S, KT) do {                         \
        S##a = *(const int4*)(Ap + (KT) * 64);         \
        S##b = *(const int4*)(Bp + (KT) * 64);         \
    } while (0)
#define STAGE_WRITE(S, BUF) do {                       \
        *(int4*)&As[(BUF) * BUFSZ + wi0] = S##a;       \
        *(int4*)&Bs[(BUF) * BUFSZ + wi0] = S##b;       \
    } while (0)
#define COMPUTE(BUF) do {                                                          \
        __builtin_amdgcn_s_setprio(1);                                             \
        _Pragma("unroll")                                                          \
        for (int ks = 0; ks < 64; ks += 32) {                                      \
            int ca = ks + quad * 8;                                                \
            int bb = (BUF) * BUFSZ;                                                \
            bf16x8 a0 = *(const bf16x8*)&As[bb + SWZI(wm +  0 + l16, ca)];         \
            bf16x8 a1 = *(const bf16x8*)&As[bb + SWZI(wm + 16 + l16, ca)];         \
            bf16x8 b0 = *(const bf16x8*)&Bs[bb + SWZI(wn +  0 + l16, ca)];         \
            bf16x8 b1 = *(const bf16x8*)&Bs[bb + SWZI(wn + 16 + l16, ca)];         \
            MFMA_BF16(acc00, a0, b0); MFMA_BF16(acc01, a0, b1);                    \
            MFMA_BF16(acc10, a1, b0); MFMA_BF16(acc11, a1, b1);                    \
        }                                                                          \
        __builtin_amdgcn_s_setprio(0);                                             \
    } while (0)

    // prologue: tiles 0,1 in flight; tile0 -> buf0; light barrier (tile1 stays in flight)
    STAGE_LOAD(s0, 0);
    STAGE_LOAD(s1, 1);
    STAGE_WRITE(s0, 0);
    LIGHT_BARRIER();

    // iter0: load tile2 at top; write tile1->buf1 (drains under MFMA); compute tile0
    STAGE_LOAD(s0, 2);
    STAGE_WRITE(s1, 1);             // buf1 never read yet; s1 loads drained at prologue
    COMPUTE(0);
    LIGHT_BARRIER();

    // iter1: load tile3; write tile2->buf0 (buf0 readers done before iter0 barrier)
    STAGE_LOAD(s1, 3);
    STAGE_WRITE(s0, 0);
    COMPUTE(1);
    LIGHT_BARRIER();

    // iter2: write tile3->buf1 (buf1 readers done before iter1 barrier); compute tile2
    STAGE_WRITE(s1, 1);
    COMPUTE(0);
    LIGHT_BARRIER();

    // iter3: compute tile3(buf1); no barrier
    COMPUTE(1);

#undef STAGE_LOAD
#undef STAGE_WRITE
#undef COMPUTE

#define EPI_STORE(accv, R, CC) do {                                          \
        int col = n0 + wn + (CC) * 16 + l16;                                 \
        float bb = bias[col];                                                \
        int rowb = m0 + wm + (R) * 16 + quad * 4;                            \
        _Pragma("unroll")                                                    \
        for (int rr = 0; rr < 4; ++rr) {                                     \
            int row = rowb + rr;                                             \
            if (row < M) {                                                   \
                float v = (accv)[rr] + bb;                                   \
                if (EPI) {                                                   \
                    v = fmaxf(v, 0.f);                                       \
                    v += bf2f(resid[(size_t)row * 256 + col]);               \
                    ((float*)C)[(size_t)row * Ncols + col] = v;              \
                } else {                                                     \
                    ((unsigned short*)C)[(size_t)row * Ncols + col] = f2bf(v);\
                }                                                            \
            }                                                                \
        }                                                                    \
    } while (0)

    EPI_STORE(acc00, 0, 0); EPI_STORE(acc01, 0, 1);
    EPI_STORE(acc10, 1, 0); EPI_STORE(acc11, 1, 1);
#undef EPI_STORE
}

// ---------- K3: edge attention + residual + LN2 — wave = node, half-wave = batch ----------
// All 16 K/V gather loads issued into named registers before compute (R9; no spill).
// Merged single dispatch (1250 blocks x 1024 thr). At its random-gather traffic floor.
__global__ __launch_bounds__(1024) void attn_kernel(
    const unsigned short* __restrict__ qkv,   // [ROWS][768] bf16: q|k|v
    const int* __restrict__ edges,            // int32 [E][2]
    const unsigned short* __restrict__ xn,    // [ROWS][256] bf16
    const float* __restrict__ g2, const float* __restrict__ b2,
    unsigned short* __restrict__ concat,      // [ROWS][256] bf16
    unsigned short* __restrict__ h2)          // [ROWS][256] bf16
{
    int wave = threadIdx.x >> 6, lane = threadIdx.x & 63;
    int i = blockIdx.x * 16 + wave;           // node id
    int b = lane >> 5, hl = lane & 31;        // batch half, 8 dims/lane
    size_t m = (size_t)b * NNODE + i;

    int jv = 0;
    if (lane < 8) jv = edges[2 * (i * 8 + lane) + 1];   // chain head: issue first

    int4 qi = *(const int4*)(qkv + m * 768 + hl * 8);
    int4 xi = *(const int4*)(xn + m * DMODEL + hl * 8);   // issued early, used late
    const unsigned short* qs = (const unsigned short*)&qi;
    float qf[8];
    #pragma unroll
    for (int t = 0; t < 8; ++t) qf[t] = bf2f(qs[t]);

#define KVLOAD(E)                                                                  \
    int j##E = __shfl(jv, E);                                                      \
    const unsigned short* kp##E = qkv + ((size_t)b * NNODE + j##E) * 768 + 256 + hl * 8; \
    int4 KI##E = *(const int4*)(kp##E);                                            \
    int4 VI##E = *(const int4*)(kp##E + 256);
    KVLOAD(0) KVLOAD(1) KVLOAD(2) KVLOAD(3)
    KVLOAD(4) KVLOAD(5) KVLOAD(6) KVLOAD(7)
#undef KVLOAD

    float acc[8] = {};
    float den = 0.f;
    const float scale = 0.17677669529663687f;           // 1/sqrt(32)
#define EDGE(E) do {                                                         \
        const unsigned short* ks = (const unsigned short*)&KI##E;            \
        const unsigned short* vs = (const unsigned short*)&VI##E;            \
        float dot = 0.f;                                                     \
        _Pragma("unroll")                                                    \
        for (int t = 0; t < 8; ++t) dot += qf[t] * bf2f(ks[t]);              \
        dot += __shfl_xor(dot, 1);                                           \
        dot += __shfl_xor(dot, 2);            /* head = 4 lanes (dh=32) */   \
        float w = __expf(dot * scale);                                       \
        _Pragma("unroll")                                                    \
        for (int t = 0; t < 8; ++t) acc[t] += w * bf2f(vs[t]);               \
        den += w;                                                            \
    } while (0)
    EDGE(0); EDGE(1); EDGE(2); EDGE(3);
    EDGE(4); EDGE(5); EDGE(6); EDGE(7);
#undef EDGE
    float inv = 1.f / den;

    const unsigned short* xs = (const unsigned short*)&xi;
    float c[8], s = 0.f, ss = 0.f;
    #pragma unroll
    for (int t = 0; t < 8; ++t) { c[t] = bf2f(xs[t]) + acc[t] * inv; s += c[t]; ss += c[t]*c[t]; }
    #pragma unroll
    for (int mk = 1; mk < 32; mk <<= 1) { s += __shfl_xor(s, mk); ss += __shfl_xor(ss, mk); }
    float mu  = s * (1.f/256.f);
    float var = ss * (1.f/256.f) - mu*mu;
    float rs  = rsqrtf(var + 1e-3f);

    float4 ga = *(const float4*)(g2 + hl * 8);
    float4 gb = *(const float4*)(g2 + hl * 8 + 4);
    float4 ba = *(const float4*)(b2 + hl * 8);
    float4 bb = *(const float4*)(b2 + hl * 8 + 4);
    float gg[8] = {ga.x, ga.y, ga.z, ga.w, gb.x, gb.y, gb.z, gb.w};
    float bv[8] = {ba.x, ba.y, ba.z, ba.w, bb.x, bb.y, bb.z, bb.w};
    unsigned short oc[8], oh[8];
    #pragma unroll
    for (int t = 0; t < 8; ++t) {
        oc[t] = f2bf(c[t]);
        oh[t] = f2bf((c[t] - mu) * rs * gg[t] + bv[t]);
    }
    *(int4*)(concat + m * DMODEL + hl * 8) = *(const int4*)oc;
    *(int4*)(h2     + m * DMODEL + hl * 8) = *(const int4*)oh;
}

// ---------- launch ----------
extern "C" void kernel_launch(void* const* d_in, const int* in_sizes, int n_in,
                              void* d_out, int out_size, void* d_ws, size_t ws_size,
                              hipStream_t stream)
{
    const float* x   = (const float*)d_in[0];
    const int* edges = (const int*)d_in[1];
    const float* wq = (const float*)d_in[2];
    const float* bq = (const float*)d_in[3];
    const float* wk = (const float*)d_in[4];
    const float* bk = (const float*)d_in[5];
    const float* wv = (const float*)d_in[6];
    const float* bv = (const float*)d_in[7];
    const float* wo = (const float*)d_in[8];
    const float* bo = (const float*)d_in[9];
    const float* g1 = (const float*)d_in[10];
    const float* b1 = (const float*)d_in[11];
    const float* g2 = (const float*)d_in[12];
    const float* b2 = (const float*)d_in[13];

    char* ws = (char*)d_ws;
    unsigned short* Wqkvt = (unsigned short*)(ws);                    // 393216 B
    unsigned short* Wot   = (unsigned short*)(ws + 393216);           // 131072 B
    float* biasq          = (float*)(ws + 393216 + 131072);           // 3072 B
    float* biaso          = (float*)(ws + 393216 + 131072 + 3072);    // 1024 B
    size_t off = 393216 + 131072 + 4096;
    unsigned short* xn     = (unsigned short*)(ws + off); off += (size_t)ROWS * DMODEL * 2;
    unsigned short* qkv    = (unsigned short*)(ws + off); off += (size_t)ROWS * 768 * 2;
    unsigned short* concat = (unsigned short*)(ws + off); off += (size_t)ROWS * DMODEL * 2;
    unsigned short* h2     = (unsigned short*)(ws + off); off += (size_t)ROWS * DMODEL * 2;

    prep_ln1_kernel<<<65 + ROWS / 8, 256, 0, stream>>>(
        wq, wk, wv, wo, bq, bk, bv, bo, x, g1, b1, Wqkvt, Wot, biasq, biaso, xn);
    gemm_kernel<false><<<dim3(313 * 6), 1024, 0, stream>>>(xn, Wqkvt, biasq, qkv, nullptr, ROWS, 768);
    attn_kernel<<<NNODE / 16, 1024, 0, stream>>>(qkv, edges, xn, g2, b2, concat, h2);
    gemm_kernel<true><<<dim3(313 * 2), 1024, 0, stream>>>(h2, Wot, biaso, d_out, concat, ROWS, 256);
}